// Round 6
// baseline (293.526 us; speedup 1.0000x reference)
//
#include <hip/hip_runtime.h>
#include <hip/hip_bf16.h>

// MambaSP R5b: ONE dispatch for all 4 layers. 1024 blocks (c=chunk, b=batch),
// co-resident by construction (128 thr, ~20KB LDS -> 7 blocks/CU >= 4 needed).
// Cross-block dataflow: publish-then-lookback flags, RELAXED polling (no
// per-poll cache invalidation -- R3's poison), single acquire fence after
// ballot (__builtin_amdgcn_fence -- __hip_atomic_fence doesn't exist here).
// All deps point to lower blockIdx. Replay-safe: ws poison resets flags;
// producers drain stores via __syncthreads then release-store the flag.

constexpr int   Bsz = 32;
constexpr int   Lsz = 4096;
constexpr int   NC  = 32;
constexpr int   CL  = 128;
constexpr int   T   = 32;            // reduction tile (time steps)
constexpr int   PSTR = 66;           // ps row stride (8B aligned, 2-way banks)
constexpr float SRinv = 1.0f / 4096.0f;

__device__ __forceinline__ float sigmoidf_(float v) {
    return 1.0f / (1.0f + __expf(-v));
}
__device__ __forceinline__ unsigned ld_flag(const unsigned* p) {
    return __hip_atomic_load(p, __ATOMIC_RELAXED, __HIP_MEMORY_SCOPE_AGENT);
}
__device__ __forceinline__ float ld_f32(const float* p) {
    unsigned u = __hip_atomic_load((const unsigned*)p, __ATOMIC_RELAXED, __HIP_MEMORY_SCOPE_AGENT);
    return __builtin_bit_cast(float, u);
}

__global__ __launch_bounds__(128) void k_fused(
    const float* __restrict__ xin,        // [B,L]
    const float* __restrict__ W_in_all,   // [4][4]
    const float* __restrict__ conv_w_all, // [4][8]
    const float* __restrict__ conv_b_all, // [4][2]
    const float* __restrict__ W_x_all,    // [4][258]
    const float* __restrict__ W_dt_all,   // [4][2]
    const float* __restrict__ b_dt_all,   // [4][2]
    const float* __restrict__ A_log_all,  // [4][128]
    const float* __restrict__ D_all,      // [4][2]
    const float* __restrict__ W_out_all,  // [4][2]
    float2*   __restrict__ PS,            // [4][B][NC][128]
    unsigned* __restrict__ fps,           // [4][B][NC]
    unsigned* __restrict__ fout,          // [3][B][NC]
    float*    __restrict__ interm,        // [3][B][L]
    float*    __restrict__ out)           // [B,L]
{
    const int c = blockIdx.x, b = blockIdx.y, tid = threadIdx.x;
    __shared__ float  xs[CL + 3];     // xs[j] = in[c*CL - 3 + j]
    __shared__ float4 s_ud[CL];       // {u0,u1,d0,d1}
    __shared__ float  ps[2 * T * PSTR];
    __shared__ float  pp[128];
    __shared__ float  s_out[CL];
    const int e = tid >> 6, n = tid & 63;   // e wave-uniform
    const int base = b * Lsz + c * CL;

    for (int i = 0; i < 4; i++) {
        const float* Wi = W_in_all   + i * 4;
        const float* cw = conv_w_all + i * 8;
        const float* cb = conv_b_all + i * 2;
        const float* Wx = W_x_all    + i * 258;
        const float* Wd = W_dt_all   + i * 2;
        const float* bd = b_dt_all   + i * 2;
        const float* Al = A_log_all  + i * 128;
        const float* Dv = D_all      + i * 2;
        const float* Wo = W_out_all  + i * 2;

        // ---- 1. input chunk + 3-halo into xs ----
        if (i == 0) {
            for (int j = tid; j < CL + 3; j += 128) {
                int l = c * CL + j - 3;
                xs[j] = (l >= 0) ? xin[b * Lsz + l] : 0.0f;
            }
        } else {
            const unsigned* fo = fout + ((size_t)(i - 1) * Bsz + b) * NC;
            if (tid < 64) {
                int cc = (tid == 0) ? c : ((tid == 1) ? c - 1 : -1);
                bool need = (cc >= 0);
                while (true) {
                    unsigned f = need ? ld_flag(&fo[cc]) : 1u;
                    if (__ballot(f != 1u) == 0ull) break;
                    __builtin_amdgcn_s_sleep(2);
                }
            }
            __syncthreads();
            __builtin_amdgcn_fence(__ATOMIC_ACQUIRE, "agent");
            const float* src = interm + (size_t)(i - 1) * Bsz * Lsz;
            xs[3 + tid] = ld_f32(&src[base + tid]);
            if (tid < 3)
                xs[tid] = (c > 0) ? ld_f32(&src[base - 3 + tid]) : 0.0f;
        }
        __syncthreads();

        // ---- 2. preprocess: thread t = chunk position t ----
        {
            const int t = tid;
            float x0 = xs[t], x1 = xs[t + 1], x2 = xs[t + 2], x3 = xs[t + 3];
            float v0 = Wi[0] * (x0 * cw[0] + x1 * cw[1] + x2 * cw[2] + x3 * cw[3]) + cb[0];
            float v1 = Wi[1] * (x0 * cw[4] + x1 * cw[5] + x2 * cw[6] + x3 * cw[7]) + cb[1];
            float u0 = v0 * sigmoidf_(v0);
            float u1 = v1 * sigmoidf_(v1);
            float dt = u0 * Wx[0] + u1 * Wx[129];
            float a0 = dt * Wd[0] + bd[0];
            float a1 = dt * Wd[1] + bd[1];
            float d0 = ((a0 > 20.0f) ? a0 : log1pf(__expf(a0))) * SRinv;
            float d1 = ((a1 > 20.0f) ? a1 : log1pf(__expf(a1))) * SRinv;
            s_ud[t] = make_float4(u0, u1, d0, d1);
        }
        __syncthreads();

        const float Aen = -__expf(Al[e * 64 + n]);
        const float wb0 = Wx[1 + n],  wb1 = Wx[129 + 1 + n];
        const float wc0 = Wx[65 + n], wc1 = Wx[129 + 65 + n];
        const float wz0 = Wi[2], wz1 = Wi[3];
        const float D0 = Dv[0], D1 = Dv[1];
        const float wo0 = Wo[0], wo1 = Wo[1];

        // ---- 3. phase A: local aggregate, publish BEFORE any wait ----
        if (c < NC - 1) {
            float P = 1.0f, S = 0.0f;
            if (e == 0) {
                #pragma unroll 8
                for (int l = 0; l < CL; l++) {
                    float4 v = s_ud[l];
                    float Bn = v.x * wb0 + v.y * wb1;
                    float dA = __expf(v.z * Aen);
                    S = dA * S + (v.z * v.x) * Bn;
                    P *= dA;
                }
            } else {
                #pragma unroll 8
                for (int l = 0; l < CL; l++) {
                    float4 v = s_ud[l];
                    float Bn = v.x * wb0 + v.y * wb1;
                    float dA = __expf(v.w * Aen);
                    S = dA * S + (v.w * v.y) * Bn;
                    P *= dA;
                }
            }
            float2 psv = make_float2(P, S);
            unsigned long long q = __builtin_bit_cast(unsigned long long, psv);
            __hip_atomic_store(
                (unsigned long long*)&PS[(((size_t)i * Bsz + b) * NC + c) * 128 + tid],
                q, __ATOMIC_RELAXED, __HIP_MEMORY_SCOPE_AGENT);
            __syncthreads();   // each wave drains vmcnt before barrier
            if (tid == 0)
                __hip_atomic_store(&fps[((size_t)i * Bsz + b) * NC + c], 1u,
                                   __ATOMIC_RELEASE, __HIP_MEMORY_SCOPE_AGENT);
        }

        // ---- 4. lookback: relaxed poll, then acquire once; batched compose ----
        float h = 0.0f;
        if (c > 0) {
            const unsigned* fp = fps + ((size_t)i * Bsz + b) * NC;
            if (tid < 64) {
                bool need = tid < c;
                while (true) {
                    unsigned f = need ? ld_flag(&fp[tid]) : 1u;
                    if (__ballot(f != 1u) == 0ull) break;
                    __builtin_amdgcn_s_sleep(2);
                }
            }
            __syncthreads();
            __builtin_amdgcn_fence(__ATOMIC_ACQUIRE, "agent");
            const unsigned long long* psq =
                (const unsigned long long*)(PS + (((size_t)i * Bsz + b) * NC) * 128 + tid);
            int cp = 0;
            while (cp + 8 <= c) {
                unsigned long long q[8];
                #pragma unroll
                for (int j = 0; j < 8; j++)
                    q[j] = __hip_atomic_load(psq + (size_t)(cp + j) * 128,
                                             __ATOMIC_RELAXED, __HIP_MEMORY_SCOPE_AGENT);
                #pragma unroll
                for (int j = 0; j < 8; j++) {
                    float2 v = __builtin_bit_cast(float2, q[j]);
                    h = v.x * h + v.y;
                }
                cp += 8;
            }
            for (; cp < c; cp++) {
                unsigned long long q = __hip_atomic_load(psq + (size_t)cp * 128,
                                                         __ATOMIC_RELAXED, __HIP_MEMORY_SCOPE_AGENT);
                float2 v = __builtin_bit_cast(float2, q);
                h = v.x * h + v.y;
            }
        }

        // ---- 5. rescan tiles + LDS n-reduction + epilogue ----
        for (int tile = 0; tile < CL / T; tile++) {
            const int t0 = tile * T;
            if (e == 0) {
                #pragma unroll 8
                for (int t = 0; t < T; t++) {
                    float4 v = s_ud[t0 + t];
                    float Bn = v.x * wb0 + v.y * wb1;
                    float Cn = v.x * wc0 + v.y * wc1;
                    float dA = __expf(v.z * Aen);
                    h = dA * h + (v.z * v.x) * Bn;
                    ps[(t * 2 + 0) * PSTR + n] = h * Cn;
                }
            } else {
                #pragma unroll 8
                for (int t = 0; t < T; t++) {
                    float4 v = s_ud[t0 + t];
                    float Bn = v.x * wb0 + v.y * wb1;
                    float Cn = v.x * wc0 + v.y * wc1;
                    float dA = __expf(v.w * Aen);
                    h = dA * h + (v.w * v.y) * Bn;
                    ps[(t * 2 + 1) * PSTR + n] = h * Cn;
                }
            }
            __syncthreads();
            {   // half-row partial sums (float2, 8B aligned since PSTR even)
                const int r = tid >> 1, half = tid & 1;
                const float2* row = (const float2*)&ps[r * PSTR + half * 32];
                float a0 = 0, a1 = 0;
                #pragma unroll
                for (int j = 0; j < 16; j += 2) {
                    float2 p0 = row[j], p1 = row[j + 1];
                    a0 += p0.x + p0.y;
                    a1 += p1.x + p1.y;
                }
                pp[tid] = a0 + a1;
            }
            __syncthreads();
            if (tid < T) {
                const int t = tid, l = t0 + t;
                float4 v = s_ud[l];
                float y0 = pp[(t * 2 + 0) * 2 + 0] + pp[(t * 2 + 0) * 2 + 1] + v.x * D0;
                float y1 = pp[(t * 2 + 1) * 2 + 0] + pp[(t * 2 + 1) * 2 + 1] + v.y * D1;
                float xv = xs[l + 3];
                float z0 = xv * wz0, z1 = xv * wz1;
                s_out[l] = y0 * (z0 * sigmoidf_(z0)) * wo0 +
                           y1 * (z1 * sigmoidf_(z1)) * wo1 + xv;
            }
            __syncthreads();
        }

        // ---- 6. write chunk output; publish flag for next layer ----
        if (i < 3) {
            float* dst = interm + (size_t)i * Bsz * Lsz;
            __hip_atomic_store((unsigned*)&dst[base + tid],
                               __builtin_bit_cast(unsigned, s_out[tid]),
                               __ATOMIC_RELAXED, __HIP_MEMORY_SCOPE_AGENT);
            __syncthreads();   // drain stores (vmcnt before barrier)
            if (tid == 0)
                __hip_atomic_store(&fout[((size_t)i * Bsz + b) * NC + c], 1u,
                                   __ATOMIC_RELEASE, __HIP_MEMORY_SCOPE_AGENT);
            __syncthreads();   // keep xs/s_ud stable until all threads done
        } else {
            out[base + tid] = s_out[tid];
        }
    }
}

extern "C" void kernel_launch(void* const* d_in, const int* in_sizes, int n_in,
                              void* d_out, int out_size, void* d_ws, size_t ws_size,
                              hipStream_t stream) {
    const float* x      = (const float*)d_in[0];
    const float* W_in   = (const float*)d_in[1];   // [4,1,4]
    const float* conv_w = (const float*)d_in[2];   // [4,2,4]
    const float* conv_b = (const float*)d_in[3];   // [4,2]
    const float* W_x    = (const float*)d_in[4];   // [4,2,129]
    const float* W_dt   = (const float*)d_in[5];   // [4,1,2]
    const float* b_dt   = (const float*)d_in[6];   // [4,2]
    const float* A_log  = (const float*)d_in[7];   // [4,2,64]
    const float* D_skip = (const float*)d_in[8];   // [4,2]
    const float* W_out  = (const float*)d_in[9];   // [4,2,1]
    float* out = (float*)d_out;

    char* ws = (char*)d_ws;
    float2*   PS     = (float2*)ws;                               // 4*B*NC*128 float2 = 4MB
    size_t    ps_bytes = (size_t)4 * Bsz * NC * 128 * sizeof(float2);
    float*    interm = (float*)(ws + ps_bytes);                   // 3*B*L floats = 1.5MB
    size_t    in_bytes = (size_t)3 * Bsz * Lsz * sizeof(float);
    unsigned* fps    = (unsigned*)(ws + ps_bytes + in_bytes);     // 4*B*NC
    unsigned* fout   = fps + (size_t)4 * Bsz * NC;                // 3*B*NC

    k_fused<<<dim3(NC, Bsz), 128, 0, stream>>>(
        x, W_in, conv_w, conv_b, W_x, W_dt, b_dt, A_log, D_skip, W_out,
        PS, fps, fout, interm, out);
}